// Round 10
// baseline (1659.905 us; speedup 1.0000x reference)
//
#include <hip/hip_runtime.h>
#include <math.h>

static inline int cdiv(int a, int b){ return (a + b - 1) / b; }

#define SCAN_CHUNK 4096   // 256 threads x 16 items
#define BCHUNK 4096       // edges per bucket-scatter block

typedef _Float16 v4h __attribute__((ext_vector_type(4)));
typedef float    v4f __attribute__((ext_vector_type(4)));
typedef _Float16 h2  __attribute__((ext_vector_type(2)));

// ---------------- graph construction (bucketed, no big global atomics) ----------------

// coarse 256-bucket histogram (bucket = dst>>9), LDS-staged
__global__ __launch_bounds__(256) void k_bcount(const int* __restrict__ dst, int E, int* __restrict__ bcnt256){
  __shared__ int h[256];
  h[threadIdx.x] = 0;
  __syncthreads();
  int stride = gridDim.x*256;
  for (int i = blockIdx.x*256 + threadIdx.x; i < E; i += stride) atomicAdd(&h[dst[i] >> 9], 1);
  __syncthreads();
  if (h[threadIdx.x]) atomicAdd(&bcnt256[threadIdx.x], h[threadIdx.x]);
}

// single-block scan of bucket counts -> bbase[0..NB], gcur seed
__global__ __launch_bounds__(256) void k_scan_b256(const int* __restrict__ bcnt256, int* __restrict__ bbase,
                          int* __restrict__ gcur, int NB){
  __shared__ int sh[256];
  int t = threadIdx.x;
  int v = (t < NB) ? bcnt256[t] : 0;
  sh[t] = v; __syncthreads();
  for (int o = 1; o < 256; o <<= 1){
    int u = (t >= o) ? sh[t-o] : 0;
    __syncthreads();
    sh[t] += u;
    __syncthreads();
  }
  int excl = sh[t] - v;
  if (t < NB){ bbase[t] = excl; gcur[t] = excl; }
  if (t == 0) bbase[NB] = sh[255];
}

// scatter packed edges into dst-bucketed array
__global__ __launch_bounds__(256) void k_bucket(const int* __restrict__ src, const int* __restrict__ dst,
                        int E, int* __restrict__ gcur, unsigned int* __restrict__ bout){
  __shared__ int lcnt[256], gbase[256];
  int t = threadIdx.x;
  lcnt[t] = 0;
  __syncthreads();
  int base = blockIdx.x*BCHUNK;
  int end = min(base + BCHUNK, E);
  for (int i = base + t; i < end; i += 256) atomicAdd(&lcnt[dst[i] >> 9], 1);
  __syncthreads();
  gbase[t] = lcnt[t] ? atomicAdd(&gcur[t], lcnt[t]) : 0;
  __syncthreads();
  lcnt[t] = 0;
  __syncthreads();
  for (int i = base + t; i < end; i += 256){
    int s = src[i], d = dst[i];
    int b = d >> 9;
    int pos = gbase[b] + atomicAdd(&lcnt[b], 1);
    bout[pos] = ((unsigned int)s << 9) | (unsigned int)(d & 511);
  }
}

// one block per bucket: LDS 512-histogram -> rowptr/dinv -> LDS-cursor fill of cols
__global__ __launch_bounds__(256) void k_build(const unsigned int* __restrict__ bout, const int* __restrict__ bbase,
                       int* __restrict__ rowptr, float* __restrict__ dinv,
                       int* __restrict__ cols, int N, int NB){
  __shared__ int cnt[512], part[256];
  int b = blockIdx.x;
  int t = threadIdx.x;
  cnt[t] = 0; cnt[t + 256] = 0;
  __syncthreads();
  int s0 = bbase[b], s1 = bbase[b+1];
  for (int i = s0 + t; i < s1; i += 256) atomicAdd(&cnt[bout[i] & 511u], 1);
  __syncthreads();
  int c0 = cnt[2*t], c1 = cnt[2*t + 1];
  part[t] = c0 + c1;
  __syncthreads();
  for (int o = 1; o < 256; o <<= 1){
    int u = (t >= o) ? part[t-o] : 0;
    __syncthreads();
    part[t] += u;
    __syncthreads();
  }
  int e0 = part[t] - (c0 + c1);
  int e1 = e0 + c0;
  int r0 = b << 9;
  int n0 = r0 + 2*t, n1 = n0 + 1;
  if (n0 < N){ rowptr[n0] = s0 + e0; dinv[n0] = rsqrtf((float)c0 + 2.f); }
  if (n1 < N){ rowptr[n1] = s0 + e1; dinv[n1] = rsqrtf((float)c1 + 2.f); }
  if (b == NB-1 && t == 0) rowptr[N] = s1;
  __syncthreads();
  cnt[2*t] = s0 + e0; cnt[2*t + 1] = s0 + e1;   // reuse as cursors
  __syncthreads();
  for (int i = s0 + t; i < s1; i += 256){
    unsigned int v = bout[i];
    int pos = atomicAdd(&cnt[v & 511u], 1);
    cols[pos] = (int)(v >> 9);
  }
}

// ---- CSR level L+1 from level L: wave-parallel (16 lanes/row), order-preserving ----

__global__ __launch_bounds__(256) void k_csr_keep(const int* __restrict__ rowptrA, const int* __restrict__ colsA,
                         const int* __restrict__ nidx, int* __restrict__ tmp,
                         int* __restrict__ cnt, int NA){
  int t = threadIdx.x;
  int g = (blockIdx.x*256 + t) >> 4;
  int lane = t & 15;
  if (g >= NA) return;
  int m = nidx[g];
  if (m < 0) return;
  int jb = rowptrA[g], je = rowptrA[g+1];
  int run = 0;
  int shift = (t & 63) & ~15;
  for (int j0 = jb; j0 < je; j0 += 16){
    int j = j0 + lane;
    int s = -1;
    if (j < je) s = nidx[colsA[j]];
    bool keep = s >= 0;
    unsigned long long bal = __ballot(keep);
    unsigned int gm = (unsigned int)(bal >> shift) & 0xFFFFu;
    if (keep) tmp[jb + run + __popc(gm & ((1u << lane) - 1))] = s;
    run += __popc(gm);
  }
  if (lane == 0) cnt[m] = run;
}

__global__ __launch_bounds__(256) void k_csr_copy(const int* __restrict__ rowptrA, const int* __restrict__ nidx,
                         const int* __restrict__ tmp, const int* __restrict__ rowptrB,
                         int* __restrict__ colsB, int NA){
  int t = threadIdx.x;
  int g = (blockIdx.x*256 + t) >> 4;
  int lane = t & 15;
  if (g >= NA) return;
  int m = nidx[g];
  if (m < 0) return;
  int jbA = rowptrA[g];
  int db = rowptrB[m], n = rowptrB[m+1] - db;
  for (int j = lane; j < n; j += 16) colsB[db + j] = tmp[jbA + j];
}

// ---------------- hierarchical exclusive scan (for derived CSR levels) ----------------

__global__ __launch_bounds__(256) void k_scan_p1(const int* __restrict__ in, int nIn, int* __restrict__ bsum){
  __shared__ int sh[256];
  int base = blockIdx.x*SCAN_CHUNK;
  int end = min(base + SCAN_CHUNK, nIn);
  int s = 0;
  for (int i = base + threadIdx.x; i < end; i += 256) s += in[i];
  sh[threadIdx.x] = s; __syncthreads();
  for (int o = 128; o > 0; o >>= 1){
    if (threadIdx.x < o) sh[threadIdx.x] += sh[threadIdx.x + o];
    __syncthreads();
  }
  if (threadIdx.x == 0) bsum[blockIdx.x] = sh[0];
}

__global__ __launch_bounds__(256) void k_scan_p2(int* __restrict__ bsum, int nb){
  __shared__ int sh[256];
  int t = threadIdx.x;
  int v = (t < nb) ? bsum[t] : 0;
  sh[t] = v; __syncthreads();
  for (int o = 1; o < 256; o <<= 1){
    int u = (t >= o) ? sh[t-o] : 0;
    __syncthreads();
    sh[t] += u;
    __syncthreads();
  }
  if (t < nb) bsum[t] = sh[t] - v;
}

__global__ __launch_bounds__(256) void k_scan_p3(const int* __restrict__ cnt, const int* __restrict__ bsum,
                        int* __restrict__ rowptr, float* __restrict__ dinv, int nIn){
  int t = threadIdx.x;
  int tb = blockIdx.x*SCAN_CHUNK + t*16;
  int my[16]; int s = 0;
#pragma unroll
  for (int j = 0; j < 16; ++j){
    int i = tb + j;
    int v = (i < nIn) ? cnt[i] : 0;
    my[j] = v; s += v;
  }
  __shared__ int sh[256];
  sh[t] = s; __syncthreads();
  for (int o = 1; o < 256; o <<= 1){
    int u = (t >= o) ? sh[t-o] : 0;
    __syncthreads();
    sh[t] += u;
    __syncthreads();
  }
  int run = bsum[blockIdx.x] + sh[t] - s;
#pragma unroll
  for (int j = 0; j < 16; ++j){
    int i = tb + j;
    if (i < nIn){
      rowptr[i] = run;
      if (dinv) dinv[i] = rsqrtf((float)my[j] + 2.0f);
      run += my[j];
    } else if (i == nIn){
      rowptr[nIn] = run;
    }
  }
}

// ---------------- W prep (element-parallel) ----------------

__global__ void k_prep_w_el(const float* __restrict__ W, const float* __restrict__ ss,
                            _Float16* __restrict__ Whi, _Float16* __restrict__ Wlo,
                            float* __restrict__ bias2, const float* __restrict__ bias,
                            int KM, int M, int mshift, int mmask){
  int idx = blockIdx.x*256 + threadIdx.x;
  if (idx >= KM) return;
  int k = idx >> mshift, m = idx & mmask;
  float w = W[idx];
  if (ss) w *= ss[k];
  _Float16 hi = (_Float16)w;
  size_t oidx = ((size_t)(k >> 2)*M + m)*4 + (k & 3);
  Whi[oidx] = hi;
  if (Wlo) Wlo[oidx] = (_Float16)(w - (float)hi);
  if (k == 0) bias2[m] = bias ? bias[m] : 0.f;
}

__global__ void k_prep_bias(const float* __restrict__ W, const float* __restrict__ ss,
                            float* __restrict__ bias2, int K, int M){
  int m = blockIdx.x;
  int lane = threadIdx.x;
  float s = 0.f;
  for (int k = lane; k < K; k += 64) s = fmaf(ss[K + k], W[(size_t)k*M + m], s);
  for (int o = 32; o > 0; o >>= 1) s += __shfl_down(s, o, 64);
  if (lane == 0) bias2[m] = s;
}

// ---------------- MFMA f16 GEMM, 64 rows/wave, optional pooled-A (perm+val) ----------------

template<int SPLIT>
__global__ __launch_bounds__(256) void k_gemm16(
    const float* __restrict__ A, const _Float16* __restrict__ Whi,
    const _Float16* __restrict__ Wlo, const float* __restrict__ bias2,
    float* __restrict__ Out32, _Float16* __restrict__ Out16,
    float* __restrict__ stats, const int* __restrict__ permA,
    const float* __restrict__ valA, int N, int K, int M, int relu)
{
  __shared__ float sacc[64], s2acc[64];
  int tid = threadIdx.x;
  if (stats){
    if (tid < 64){ sacc[tid] = 0.f; s2acc[tid] = 0.f; }
    __syncthreads();
  }
  int wave = tid >> 6, lane = tid & 63;
  int g = lane >> 4, r = lane & 15;
  int wrow0 = blockIdx.x*256 + wave*64;
  int col0 = blockIdx.y*64;
  int nf = (M - col0) >> 4; if (nf > 4) nf = 4;

  int srow[4]; float sclr[4];
#pragma unroll
  for (int rt = 0; rt < 4; ++rt){
    int arow = wrow0 + rt*16 + r;
    if (arow < N){
      int sr = permA ? permA[arow] : arow;
      srow[rt] = sr;
      sclr[rt] = permA ? valA[sr] : 1.f;
    } else { srow[rt] = -1; sclr[rt] = 0.f; }
  }

  v4f acc[4][4];
#pragma unroll
  for (int rt = 0; rt < 4; ++rt)
#pragma unroll
    for (int c = 0; c < 4; ++c) acc[rt][c] = (v4f){0.f,0.f,0.f,0.f};

  for (int k0 = 0; k0 < K; k0 += 16){
    int kb = (k0 >> 2) + g;
    v4h bh[4], bl[4];
#pragma unroll
    for (int c = 0; c < 4; ++c){
      if (c >= nf) continue;
      size_t bidx = ((size_t)kb*M + col0 + c*16 + r)*4;
      bh[c] = *(const v4h*)&Whi[bidx];
      if (SPLIT) bl[c] = *(const v4h*)&Wlo[bidx];
    }
    v4h ah[4], al[4];
#pragma unroll
    for (int rt = 0; rt < 4; ++rt){
      if (srow[rt] >= 0){
        float4 av = *(const float4*)&A[(size_t)srow[rt]*K + k0 + g*4];
        float xs[4] = {av.x*sclr[rt], av.y*sclr[rt], av.z*sclr[rt], av.w*sclr[rt]};
#pragma unroll
        for (int j = 0; j < 4; ++j){
          _Float16 hi = (_Float16)xs[j];
          ah[rt][j] = hi;
          if (SPLIT) al[rt][j] = (_Float16)(xs[j] - (float)hi);
        }
      } else {
#pragma unroll
        for (int j = 0; j < 4; ++j){ ah[rt][j] = (_Float16)0.f; if (SPLIT) al[rt][j] = (_Float16)0.f; }
      }
    }
#pragma unroll
    for (int rt = 0; rt < 4; ++rt){
#pragma unroll
      for (int c = 0; c < 4; ++c){
        if (c >= nf) continue;
        acc[rt][c] = __builtin_amdgcn_mfma_f32_16x16x16f16(ah[rt], bh[c], acc[rt][c], 0, 0, 0);
        if (SPLIT){
          acc[rt][c] = __builtin_amdgcn_mfma_f32_16x16x16f16(al[rt], bh[c], acc[rt][c], 0, 0, 0);
          acc[rt][c] = __builtin_amdgcn_mfma_f32_16x16x16f16(ah[rt], bl[c], acc[rt][c], 0, 0, 0);
        }
      }
    }
  }

#pragma unroll
  for (int c = 0; c < 4; ++c){
    if (c >= nf) continue;
    int col = col0 + c*16 + r;
    float bsv = bias2[col];
    float s = 0.f, s2 = 0.f;
#pragma unroll
    for (int rt = 0; rt < 4; ++rt){
#pragma unroll
      for (int i = 0; i < 4; ++i){
        int rr = wrow0 + rt*16 + g*4 + i;
        float v = acc[rt][c][i] + bsv;
        if (relu) v = fmaxf(v, 0.f);
        if (rr < N){
          if (Out32) Out32[(size_t)rr*M + col] = v;
          if (Out16) Out16[(size_t)rr*M + col] = (_Float16)v;
          s += v; s2 = fmaf(v, v, s2);
        }
      }
    }
    if (stats){
      s  += __shfl_xor(s, 16);  s  += __shfl_xor(s, 32);
      s2 += __shfl_xor(s2, 16); s2 += __shfl_xor(s2, 32);
      if (g == 0){
        atomicAdd(&sacc[c*16 + r], s);
        atomicAdd(&s2acc[c*16 + r], s2);
      }
    }
  }
  if (stats){
    __syncthreads();
    if (tid < 64 && col0 + tid < M){
      atomicAdd(&stats[col0 + tid], sacc[tid]);
      atomicAdd(&stats[M + col0 + tid], s2acc[tid]);
    }
  }
}

// ---------------- batch norm ----------------

__global__ void k_bn_final(const float* __restrict__ acc, const float* __restrict__ g,
                           const float* __restrict__ b, float* __restrict__ ss, int N, int C){
  int c = threadIdx.x;
  if (c >= C) return;
  float mu  = acc[c] / (float)N;
  float var = acc[C + c] / (float)N - mu*mu;
  float sc  = rsqrtf(var + 1e-5f) * g[c];
  ss[c]     = sc;
  ss[C + c] = b[c] - mu*sc;
}

__global__ void k_bn_apply(const float* __restrict__ X, float* __restrict__ Y,
                           const float* __restrict__ ss, int total, int C, int relu){
  int i = blockIdx.x*blockDim.x + threadIdx.x;
  if (i >= total) return;
  int c = i % C;
  float v = X[i]*ss[c] + ss[C + c];
  if (relu) v = fmaxf(v, 0.f);
  Y[i] = v;
}

// fused BN-apply(+relu) + pooling score (one wave per node)
__global__ void k_bnap_score(const float* __restrict__ X, float* __restrict__ Y,
                             const float* __restrict__ ss, const float* __restrict__ p,
                             float* __restrict__ val, unsigned int* __restrict__ key,
                             int N, int C){
  int wid  = (blockIdx.x*blockDim.x + threadIdx.x) >> 6;
  int lane = threadIdx.x & 63;
  if (wid >= N) return;
  float s = 0.f, np = 0.f;
  for (int c = lane; c < C; c += 64){
    float v = X[(size_t)wid*C + c]*ss[c] + ss[C + c];
    v = fmaxf(v, 0.f);
    Y[(size_t)wid*C + c] = v;
    float pv = p[c];
    s = fmaf(v, pv, s);
    np = fmaf(pv, pv, np);
  }
  for (int o = 32; o > 0; o >>= 1){ s += __shfl_down(s, o, 64); np += __shfl_down(np, o, 64); }
  if (lane == 0){
    float sc = tanhf(s * rsqrtf(np));
    val[wid] = sc;
    unsigned int b = __float_as_uint(sc);
    key[wid] = (b & 0x80000000u) ? ~b : (b | 0x80000000u);
  }
}

// ---------------- GCN aggregation (pair-vectorized + 4-edge ILP + fused stats) ----------------

__device__ inline float2 ldpair(const float* h, size_t off){
  return *(const float2*)(h + off);
}
__device__ inline float2 ldpair(const _Float16* h, size_t off){
  h2 v = *(const h2*)(h + off);
  return make_float2((float)v[0], (float)v[1]);
}

template<int C, typename T>
__global__ void k_agg(const T* __restrict__ h, const int* __restrict__ rowptr,
                      const int* __restrict__ cols, const float* __restrict__ dinv,
                      const float* __restrict__ bias, float* __restrict__ out,
                      float* __restrict__ stats, int N, int relu)
{
  constexpr int PAIRS = C/2;
  constexpr int TPN = (PAIRS < 64) ? PAIRS : 64;
  constexpr int R = PAIRS / TPN;
  __shared__ float ls[256], ls2[256];
  int t = threadIdx.x;
  if (stats){
    ls[t] = 0.f; ls2[t] = 0.f;
    __syncthreads();
  }
  int gid  = blockIdx.x*blockDim.x + t;
  int node = gid / TPN;
  int lane = gid % TPN;
  bool act = node < N;
  float2 vv[R];
  if (act){
    float di = dinv[node];
    float2 acc[R];
#pragma unroll
    for (int r = 0; r < R; ++r) acc[r] = make_float2(0.f, 0.f);
    int j  = rowptr[node];
    int je = rowptr[node+1];
    for (; j + 4 <= je; j += 4){
      int s0 = cols[j], s1 = cols[j+1], s2 = cols[j+2], s3 = cols[j+3];
      float w0 = dinv[s0]*di, w1 = dinv[s1]*di, w2 = dinv[s2]*di, w3 = dinv[s3]*di;
#pragma unroll
      for (int r = 0; r < R; ++r){
        size_t po = (size_t)(lane + r*TPN)*2;
        float2 h0 = ldpair(h, (size_t)s0*C + po);
        float2 h1 = ldpair(h, (size_t)s1*C + po);
        float2 h2v = ldpair(h, (size_t)s2*C + po);
        float2 h3 = ldpair(h, (size_t)s3*C + po);
        acc[r].x = fmaf(w0, h0.x, acc[r].x); acc[r].y = fmaf(w0, h0.y, acc[r].y);
        acc[r].x = fmaf(w1, h1.x, acc[r].x); acc[r].y = fmaf(w1, h1.y, acc[r].y);
        acc[r].x = fmaf(w2, h2v.x, acc[r].x); acc[r].y = fmaf(w2, h2v.y, acc[r].y);
        acc[r].x = fmaf(w3, h3.x, acc[r].x); acc[r].y = fmaf(w3, h3.y, acc[r].y);
      }
    }
    for (; j < je; ++j){
      int s = cols[j];
      float wgt = dinv[s]*di;
#pragma unroll
      for (int r = 0; r < R; ++r){
        float2 hv = ldpair(h, (size_t)s*C + (size_t)(lane + r*TPN)*2);
        acc[r].x = fmaf(wgt, hv.x, acc[r].x);
        acc[r].y = fmaf(wgt, hv.y, acc[r].y);
      }
    }
    float sw = 2.f*di*di;
#pragma unroll
    for (int r = 0; r < R; ++r){
      int pc = (lane + r*TPN)*2;
      float2 hv = ldpair(h, (size_t)node*C + pc);
      float2 v;
      v.x = acc[r].x + sw*hv.x + bias[pc];
      v.y = acc[r].y + sw*hv.y + bias[pc+1];
      if (relu){ v.x = fmaxf(v.x, 0.f); v.y = fmaxf(v.y, 0.f); }
      *(float2*)&out[(size_t)node*C + pc] = v;
      vv[r] = v;
    }
  }
  if (stats){
    if (act){
#pragma unroll
      for (int r = 0; r < R; ++r){
        int pc = (lane + r*TPN)*2;
        atomicAdd(&ls[pc], vv[r].x);
        atomicAdd(&ls[pc+1], vv[r].y);
        atomicAdd(&ls2[pc], vv[r].x*vv[r].x);
        atomicAdd(&ls2[pc+1], vv[r].y*vv[r].y);
      }
    }
    __syncthreads();
    if (t < C){
      atomicAdd(&stats[t], ls[t]);
      atomicAdd(&stats[C + t], ls2[t]);
    }
  }
}

template<typename T>
static void launch_agg(const T* h, const int* rp, const int* cl, const float* dv,
                       const float* bias, float* o, float* stats, int N, int C, int relu,
                       hipStream_t stream){
  int tpn = (C/2 < 64) ? C/2 : 64;
  dim3 g(cdiv(N*tpn, 256));
  switch (C){
    case 16:  k_agg<16,T> <<<g, dim3(256), 0, stream>>>(h, rp, cl, dv, bias, o, stats, N, relu); break;
    case 64:  k_agg<64,T> <<<g, dim3(256), 0, stream>>>(h, rp, cl, dv, bias, o, stats, N, relu); break;
    case 128: k_agg<128,T><<<g, dim3(256), 0, stream>>>(h, rp, cl, dv, bias, o, stats, N, relu); break;
    case 256: k_agg<256,T><<<g, dim3(256), 0, stream>>>(h, rp, cl, dv, bias, o, stats, N, relu); break;
  }
}

// ---------------- top-k selection machinery ----------------

__global__ void k_hist_hi(const unsigned int* __restrict__ key, int N, unsigned int* __restrict__ hist){
  int i = blockIdx.x*blockDim.x + threadIdx.x;
  if (i < N) atomicAdd(&hist[key[i] >> 16], 1u);
}

__global__ void k_hist_lo(const unsigned int* __restrict__ key, int N,
                          const int* __restrict__ state, unsigned int* __restrict__ hist){
  int i = blockIdx.x*blockDim.x + threadIdx.x;
  if (i >= N) return;
  unsigned int kk = key[i];
  if ((int)(kk >> 16) == state[1]) atomicAdd(&hist[kk & 0xffffu], 1u);
}

// per-256-bin partial sums (256 blocks x 256 threads)
__global__ __launch_bounds__(256) void k_hsum(const unsigned int* __restrict__ hist, unsigned int* __restrict__ hsum){
  __shared__ unsigned int sh[256];
  unsigned int v = hist[blockIdx.x*256 + threadIdx.x];
  sh[threadIdx.x] = v; __syncthreads();
  for (int o = 128; o > 0; o >>= 1){
    if (threadIdx.x < o) sh[threadIdx.x] += sh[threadIdx.x + o];
    __syncthreads();
  }
  if (threadIdx.x == 0) hsum[blockIdx.x] = sh[0];
}

// single small block: pick threshold bin from hsum + one 256-bin stripe of hist
__global__ __launch_bounds__(256) void k_hpick(const unsigned int* __restrict__ hist, const unsigned int* __restrict__ hsum,
                       int* __restrict__ state, int karg, int kidx, int bidx, int ridx){
  __shared__ unsigned int sh[256];
  __shared__ int Bsel;
  __shared__ unsigned int aboveB;
  int t = threadIdx.x;
  unsigned int v = hsum[t];
  sh[t] = v; __syncthreads();
  for (int o = 1; o < 256; o <<= 1){            // suffix-inclusive
    unsigned int u = (t + o < 256) ? sh[t + o] : 0u;
    __syncthreads();
    sh[t] += u;
    __syncthreads();
  }
  unsigned int k = (unsigned int)((kidx >= 0) ? state[kidx] : karg);
  unsigned int above = sh[t] - v;
  if (above < k && sh[t] >= k){ Bsel = t; aboveB = above; }
  __syncthreads();
  int B = Bsel; unsigned int ab = aboveB;
  unsigned int c = hist[B*256 + t];
  sh[t] = c; __syncthreads();
  for (int o = 1; o < 256; o <<= 1){
    unsigned int u = (t + o < 256) ? sh[t + o] : 0u;
    __syncthreads();
    sh[t] += u;
    __syncthreads();
  }
  unsigned int above2 = ab + sh[t] - c;
  if (above2 < k && above2 + c >= k){ state[bidx] = B*256 + t; state[ridx] = (int)(k - above2); }
}

__global__ __launch_bounds__(256) void k_sel_p1(const unsigned int* __restrict__ key, int n,
                       const int* __restrict__ state, int2* __restrict__ bcnt){
  unsigned int T = ((unsigned int)state[1] << 16) | (unsigned int)state[3];
  int base = blockIdx.x*SCAN_CHUNK;
  int end = min(base + SCAN_CHUNK, n);
  int gt = 0, eq = 0;
  for (int i = base + threadIdx.x; i < end; i += 256){
    unsigned int v = key[i];
    gt += (v > T); eq += (v == T);
  }
  __shared__ int sg[256], se[256];
  sg[threadIdx.x] = gt; se[threadIdx.x] = eq;
  __syncthreads();
  for (int o = 128; o > 0; o >>= 1){
    if (threadIdx.x < o){ sg[threadIdx.x] += sg[threadIdx.x + o]; se[threadIdx.x] += se[threadIdx.x + o]; }
    __syncthreads();
  }
  if (threadIdx.x == 0) bcnt[blockIdx.x] = make_int2(sg[0], se[0]);
}

__global__ __launch_bounds__(256) void k_sel_p2(int2* __restrict__ bcnt, int nb){
  __shared__ int sg[256], se[256];
  int t = threadIdx.x;
  int2 v = (t < nb) ? bcnt[t] : make_int2(0, 0);
  sg[t] = v.x; se[t] = v.y; __syncthreads();
  for (int o = 1; o < 256; o <<= 1){
    int a = (t >= o) ? sg[t-o] : 0;
    int b = (t >= o) ? se[t-o] : 0;
    __syncthreads();
    sg[t] += a; se[t] += b;
    __syncthreads();
  }
  if (t < nb) bcnt[t] = make_int2(sg[t] - v.x, se[t] - v.y);
}

__global__ __launch_bounds__(256) void k_sel_p3(const unsigned int* __restrict__ key, int n,
                       const int* __restrict__ state, const int2* __restrict__ bcnt,
                       int* __restrict__ nidx, int* __restrict__ perm){
  unsigned int T = ((unsigned int)state[1] << 16) | (unsigned int)state[3];
  int m = state[4];
  int t = threadIdx.x;
  int tb = blockIdx.x*SCAN_CHUNK + t*16;
  unsigned int kk[16];
  int gt = 0, eq = 0;
#pragma unroll
  for (int j = 0; j < 16; ++j){
    int i = tb + j;
    bool ok = i < n;
    unsigned int v = ok ? key[i] : 0u;
    kk[j] = v;
    gt += (ok && v > T); eq += (ok && v == T);
  }
  __shared__ unsigned long long sh[256];
  unsigned long long mine = ((unsigned long long)(unsigned)gt << 32) | (unsigned)eq;
  sh[t] = mine; __syncthreads();
  for (int o = 1; o < 256; o <<= 1){
    unsigned long long u = (t >= o) ? sh[t-o] : 0ull;
    __syncthreads();
    sh[t] += u;
    __syncthreads();
  }
  unsigned long long excl = sh[t] - mine;
  int2 bo = bcnt[blockIdx.x];
  int gb = bo.x + (int)(excl >> 32);
  int eb = bo.y + (int)(excl & 0xffffffffu);
#pragma unroll
  for (int j = 0; j < 16; ++j){
    int i = tb + j;
    if (i >= n) break;
    unsigned int v = kk[j];
    bool g = v > T, e = v == T;
    bool sel = g || (e && eb < m);
    if (sel){
      int ni = gb + (eb < m ? eb : m);
      nidx[i] = ni;
      perm[ni] = i;
    } else nidx[i] = -1;
    gb += g; eb += e;
  }
}

__global__ void k_unpool(float* __restrict__ X, const float* __restrict__ D,
                         const int* __restrict__ nidx, int N, int C){
  int i = blockIdx.x*blockDim.x + threadIdx.x;
  int n = i / C, c = i % C;
  if (n >= N) return;
  int m = nidx[n];
  if (m >= 0) X[i] = (D[(size_t)m*C + c] + X[i])*0.5f;
}

// ---------------- launch ----------------

extern "C" void kernel_launch(void* const* d_in, const int* in_sizes, int n_in,
                              void* d_out, int out_size, void* d_ws, size_t ws_size,
                              hipStream_t stream)
{
  const float* x_in = (const float*)d_in[0];
  const int*   esrc = (const int*)d_in[1];
  const int*   edst = (const int*)d_in[2];
  const float* e0_mlp_W = (const float*)d_in[3];
  const float* e0_mlp_b = (const float*)d_in[4];
  const float* e0_bn1_g = (const float*)d_in[5];
  const float* e0_bn1_b = (const float*)d_in[6];
  const float* e0_conv_W= (const float*)d_in[7];
  const float* e0_conv_b= (const float*)d_in[8];
  const float* e0_n_g   = (const float*)d_in[9];
  const float* e0_n_b   = (const float*)d_in[10];
  const float* e1_p     = (const float*)d_in[11];
  const float* e1_mlp_W = (const float*)d_in[12];
  const float* e1_mlp_b = (const float*)d_in[13];
  const float* e1_bn1_g = (const float*)d_in[14];
  const float* e1_bn1_b = (const float*)d_in[15];
  const float* e1_conv_W= (const float*)d_in[16];
  const float* e1_conv_b= (const float*)d_in[17];
  const float* e1_n_g   = (const float*)d_in[18];
  const float* e1_n_b   = (const float*)d_in[19];
  const float* e2_p     = (const float*)d_in[20];
  const float* e2_mlp_W = (const float*)d_in[21];
  const float* e2_mlp_b = (const float*)d_in[22];
  const float* e2_bn1_g = (const float*)d_in[23];
  const float* e2_bn1_b = (const float*)d_in[24];
  const float* e2_conv_W= (const float*)d_in[25];
  const float* e2_conv_b= (const float*)d_in[26];
  const float* e2_n_g   = (const float*)d_in[27];
  const float* e2_n_b   = (const float*)d_in[28];
  const float* d2_W = (const float*)d_in[29];
  const float* d2_b = (const float*)d_in[30];
  const float* d1_W = (const float*)d_in[31];
  const float* d1_b = (const float*)d_in[32];
  const float* d0_W = (const float*)d_in[33];
  const float* d0_b = (const float*)d_in[34];
  float* out = (float*)d_out;

  const int N0 = in_sizes[0] / 16;
  const int E  = in_sizes[1];
  const int N1 = (N0 + 1) / 2;
  const int N2 = (N1 + 1) / 2;
  const int NB0 = cdiv(N0, 512);

  // ---- workspace carve ----
  char* w = (char*)d_ws;
  auto alloc = [&](size_t b)->void*{ void* p = (void*)w; w += (b + 255) & ~(size_t)255; return p; };
  float* x1 = (float*)alloc((size_t)N0*64*4);
  float* x2 = (float*)alloc((size_t)N1*128*4);
  float* x3 = (float*)alloc((size_t)N2*256*4);
  size_t tmax = (size_t)N0*64*4;
  float* tA = (float*)alloc(tmax);
  float* tB = (float*)alloc(tmax);
  _Float16* h16 = (_Float16*)alloc((size_t)N0*64*2);
  int* rowptr0 = (int*)alloc((size_t)(N0+1)*4);
  int* rowptr1 = (int*)alloc((size_t)(N1+1)*4);
  int* rowptr2 = (int*)alloc((size_t)(N2+1)*4);
  int* cnt  = (int*)alloc((size_t)(N0+1)*4);
  int* cols0 = (int*)alloc((size_t)E*4);
  int* cols1 = (int*)alloc((size_t)E*4);
  int* cols2 = (int*)alloc((size_t)E*4);
  float* dinv0 = (float*)alloc((size_t)N0*4);
  float* dinv1 = (float*)alloc((size_t)N1*4);
  float* dinv2 = (float*)alloc((size_t)N2*4);
  int* nidx1 = (int*)alloc((size_t)N0*4);
  int* nidx2 = (int*)alloc((size_t)N1*4);
  int* perm1 = (int*)alloc((size_t)N1*4);
  int* perm2 = (int*)alloc((size_t)N2*4);
  float* val = (float*)alloc((size_t)N0*4);
  unsigned int* key = (unsigned int*)alloc((size_t)N0*4);
  unsigned int* hist = (unsigned int*)alloc((size_t)65536*4);
  unsigned int* hsum = (unsigned int*)alloc(256*4);
  int* state = (int*)alloc(64);
  int* bsum = (int*)alloc(1024*4);
  int2* bcnt = (int2*)alloc(1024*8);
  int* gcur = (int*)alloc(256*4);
  int* bcnt256 = (int*)alloc(256*4);
  int* bbase = (int*)alloc(257*4);
  float* bnacc = (float*)alloc(512*4);
  float* ss = (float*)alloc(512*4);
  _Float16* whi = (_Float16*)alloc((size_t)256*256*2);
  _Float16* wlo = (_Float16*)alloc((size_t)256*256*2);
  float* bias2 = (float*)alloc(256*4);
  if ((size_t)(w - (char*)d_ws) > ws_size) return;
  unsigned int* bout = (unsigned int*)tA;   // alias (CSR0 build window)
  int* tmpE = (int*)tA;                     // alias (CSR-derive window)

  auto run_prep = [&](const float* W, const float* bias, int K, int M, int split){
    int KM = K*M;
    k_prep_w_el<<<dim3(cdiv(KM,256)), dim3(256), 0, stream>>>(
        W, nullptr, whi, split ? wlo : nullptr, bias2, bias, KM, M, __builtin_ctz(M), M-1);
  };
  auto run_prep_bn = [&](const float* W, const float* g, const float* b, int Ncount, int K, int M, int split){
    k_bn_final<<<dim3(1), dim3(K), 0, stream>>>(bnacc, g, b, ss, Ncount, K);
    int KM = K*M;
    k_prep_w_el<<<dim3(cdiv(KM,256)), dim3(256), 0, stream>>>(
        W, ss, whi, split ? wlo : nullptr, bias2, nullptr, KM, M, __builtin_ctz(M), M-1);
    k_prep_bias<<<dim3(M), dim3(64), 0, stream>>>(W, ss, bias2, K, M);
  };
  auto run_gemm = [&](const float* A, float* O32, _Float16* O16, float* stats,
                      const int* perm, int N, int K, int M, int act, int split){
    dim3 grd(cdiv(N,256), cdiv(M,64));
    if (split)
      k_gemm16<1><<<grd, dim3(256), 0, stream>>>(A, whi, wlo, bias2, O32, O16, stats, perm, val, N, K, M, act);
    else
      k_gemm16<0><<<grd, dim3(256), 0, stream>>>(A, whi, wlo, bias2, O32, O16, stats, perm, val, N, K, M, act);
  };
  auto run_scan = [&](const int* in, int* rowptr, float* dinv, int nIn){
    int nb = cdiv(nIn + 1, SCAN_CHUNK);
    k_scan_p1<<<dim3(nb), dim3(256), 0, stream>>>(in, nIn, bsum);
    k_scan_p2<<<dim3(1), dim3(256), 0, stream>>>(bsum, nb);
    k_scan_p3<<<dim3(nb), dim3(256), 0, stream>>>(in, bsum, rowptr, dinv, nIn);
  };
  auto run_topk_rest = [&](int N, int k, int* nidx, int* perm){
    hipMemsetAsync(hist, 0, 65536*4, stream);
    k_hist_hi<<<dim3(cdiv(N,256)), dim3(256), 0, stream>>>(key, N, hist);
    k_hsum<<<dim3(256), dim3(256), 0, stream>>>(hist, hsum);
    k_hpick<<<dim3(1), dim3(256), 0, stream>>>(hist, hsum, state, k, -1, 1, 2);
    hipMemsetAsync(hist, 0, 65536*4, stream);
    k_hist_lo<<<dim3(cdiv(N,256)), dim3(256), 0, stream>>>(key, N, state, hist);
    k_hsum<<<dim3(256), dim3(256), 0, stream>>>(hist, hsum);
    k_hpick<<<dim3(1), dim3(256), 0, stream>>>(hist, hsum, state, 0, 2, 3, 4);
    int nb = cdiv(N, SCAN_CHUNK);
    k_sel_p1<<<dim3(nb), dim3(256), 0, stream>>>(key, N, state, bcnt);
    k_sel_p2<<<dim3(1), dim3(256), 0, stream>>>(bcnt, nb);
    k_sel_p3<<<dim3(nb), dim3(256), 0, stream>>>(key, N, state, bcnt, nidx, perm);
  };
  auto run_csr_derive = [&](const int* rpA, const int* clA, const int* nidx,
                            int* rpB, int* clB, float* dvB, int NA, int NB){
    k_csr_keep<<<dim3(cdiv(NA*16,256)), dim3(256), 0, stream>>>(rpA, clA, nidx, tmpE, cnt, NA);
    run_scan(cnt, rpB, dvB, NB);
    k_csr_copy<<<dim3(cdiv(NA*16,256)), dim3(256), 0, stream>>>(rpA, nidx, tmpE, rpB, clB, NA);
  };

  // ---- CSR level 0: bucketed build (no big global atomics) ----
  hipMemsetAsync(bcnt256, 0, 256*4, stream);
  k_bcount<<<dim3(64), dim3(256), 0, stream>>>(edst, E, bcnt256);
  k_scan_b256<<<dim3(1), dim3(256), 0, stream>>>(bcnt256, bbase, gcur, NB0);
  k_bucket<<<dim3(cdiv(E,BCHUNK)), dim3(256), 0, stream>>>(esrc, edst, E, gcur, bout);
  k_build<<<dim3(NB0), dim3(256), 0, stream>>>(bout, bbase, rowptr0, dinv0, cols0, N0, NB0);

  // ---- encoder0 (split path: feeds pool1+pool2 selections) ----
  hipMemsetAsync(bnacc, 0, 2*64*4, stream);
  run_prep(e0_mlp_W, e0_mlp_b, 16, 64, 1);
  run_gemm(x_in, tA, nullptr, bnacc, nullptr, N0, 16, 64, 1, 1);
  run_prep_bn(e0_conv_W, e0_bn1_g, e0_bn1_b, N0, 64, 64, 1);
  run_gemm(tA, tB, nullptr, nullptr, nullptr, N0, 64, 64, 0, 1);
  hipMemsetAsync(bnacc, 0, 2*64*4, stream);
  launch_agg<float>(tB, rowptr0, cols0, dinv0, e0_conv_b, tA, bnacc, N0, 64, 0, stream);
  k_bn_final<<<dim3(1), dim3(64), 0, stream>>>(bnacc, e0_n_g, e0_n_b, ss, N0, 64);
  k_bnap_score<<<dim3(cdiv(N0*64,256)), dim3(256), 0, stream>>>(tA, x1, ss, e1_p, val, key, N0, 64);

  // ---- pool1 + CSR level 1 (derived from CSR0, wave-parallel) ----
  run_topk_rest(N0, N1, nidx1, perm1);
  run_csr_derive(rowptr0, cols0, nidx1, rowptr1, cols1, dinv1, N0, N1);

  // ---- encoder1 (split path: feeds pool2 selection; pooled-A fused) ----
  hipMemsetAsync(bnacc, 0, 2*128*4, stream);
  run_prep(e1_mlp_W, e1_mlp_b, 64, 128, 1);
  run_gemm(x1, tB, nullptr, bnacc, perm1, N1, 64, 128, 1, 1);
  run_prep_bn(e1_conv_W, e1_bn1_g, e1_bn1_b, N1, 128, 128, 1);
  run_gemm(tB, tA, nullptr, nullptr, nullptr, N1, 128, 128, 0, 1);
  hipMemsetAsync(bnacc, 0, 2*128*4, stream);
  launch_agg<float>(tA, rowptr1, cols1, dinv1, e1_conv_b, tB, bnacc, N1, 128, 0, stream);
  k_bn_final<<<dim3(1), dim3(128), 0, stream>>>(bnacc, e1_n_g, e1_n_b, ss, N1, 128);
  k_bnap_score<<<dim3(cdiv(N1*64,256)), dim3(256), 0, stream>>>(tB, x2, ss, e2_p, val, key, N1, 128);

  // ---- pool2 + CSR level 2 ----
  run_topk_rest(N1, N2, nidx2, perm2);
  run_csr_derive(rowptr1, cols1, nidx2, rowptr2, cols2, dinv2, N1, N2);

  // ---- encoder2 (smooth path: plain f16, f16 gather; pooled-A fused) ----
  hipMemsetAsync(bnacc, 0, 2*256*4, stream);
  run_prep(e2_mlp_W, e2_mlp_b, 128, 256, 0);
  run_gemm(x2, tB, nullptr, bnacc, perm2, N2, 128, 256, 1, 0);
  run_prep_bn(e2_conv_W, e2_bn1_g, e2_bn1_b, N2, 256, 256, 0);
  run_gemm(tB, nullptr, h16, nullptr, nullptr, N2, 256, 256, 0, 0);
  hipMemsetAsync(bnacc, 0, 2*256*4, stream);
  launch_agg<_Float16>(h16, rowptr2, cols2, dinv2, e2_conv_b, tB, bnacc, N2, 256, 0, stream);
  k_bn_final<<<dim3(1), dim3(256), 0, stream>>>(bnacc, e2_n_g, e2_n_b, ss, N2, 256);
  k_bn_apply<<<dim3(cdiv(N2*256,256)), dim3(256), 0, stream>>>(tB, x3, ss, N2*256, 256, 1);

  // ---- decoder2 + unpool into x2 ----
  run_prep(d2_W, nullptr, 256, 128, 0);
  run_gemm(x3, nullptr, h16, nullptr, nullptr, N2, 256, 128, 0, 0);
  launch_agg<_Float16>(h16, rowptr2, cols2, dinv2, d2_b, tB, nullptr, N2, 128, 1, stream);
  k_unpool<<<dim3(cdiv(N1*128,256)), dim3(256), 0, stream>>>(x2, tB, nidx2, N1, 128);

  // ---- decoder1 + unpool into x1 ----
  run_prep(d1_W, nullptr, 128, 64, 0);
  run_gemm(x2, nullptr, h16, nullptr, nullptr, N1, 128, 64, 0, 0);
  launch_agg<_Float16>(h16, rowptr1, cols1, dinv1, d1_b, tB, nullptr, N1, 64, 1, stream);
  k_unpool<<<dim3(cdiv(N0*64,256)), dim3(256), 0, stream>>>(x1, tB, nidx1, N0, 64);

  // ---- decoder0 -> output ----
  run_prep(d0_W, nullptr, 64, 16, 0);
  run_gemm(x1, nullptr, h16, nullptr, nullptr, N0, 64, 16, 0, 0);
  launch_agg<_Float16>(h16, rowptr0, cols0, dinv0, d0_b, out, nullptr, N0, 16, 0, stream);
}

// Round 11
// 1035.440 us; speedup vs baseline: 1.6031x; 1.6031x over previous
//
#include <hip/hip_runtime.h>
#include <math.h>

static inline int cdiv(int a, int b){ return (a + b - 1) / b; }

#define SCAN_CHUNK 4096   // 256 threads x 16 items
#define BCHUNK 4096       // edges per bucket-scatter block

typedef _Float16 v4h __attribute__((ext_vector_type(4)));
typedef float    v4f __attribute__((ext_vector_type(4)));
typedef _Float16 h2  __attribute__((ext_vector_type(2)));

// ---------------- graph construction (bucketed, no big global atomics) ----------------

__global__ __launch_bounds__(256) void k_bcount(const int* __restrict__ dst, int E, int* __restrict__ bcnt256){
  __shared__ int h[256];
  h[threadIdx.x] = 0;
  __syncthreads();
  int stride = gridDim.x*256;
  for (int i = blockIdx.x*256 + threadIdx.x; i < E; i += stride) atomicAdd(&h[dst[i] >> 9], 1);
  __syncthreads();
  if (h[threadIdx.x]) atomicAdd(&bcnt256[threadIdx.x], h[threadIdx.x]);
}

__global__ __launch_bounds__(256) void k_scan_b256(const int* __restrict__ bcnt256, int* __restrict__ bbase,
                          int* __restrict__ gcur, int NB){
  __shared__ int sh[256];
  int t = threadIdx.x;
  int v = (t < NB) ? bcnt256[t] : 0;
  sh[t] = v; __syncthreads();
  for (int o = 1; o < 256; o <<= 1){
    int u = (t >= o) ? sh[t-o] : 0;
    __syncthreads();
    sh[t] += u;
    __syncthreads();
  }
  int excl = sh[t] - v;
  if (t < NB){ bbase[t] = excl; gcur[t] = excl; }
  if (t == 0) bbase[NB] = sh[255];
}

__global__ __launch_bounds__(256) void k_bucket(const int* __restrict__ src, const int* __restrict__ dst,
                        int E, int* __restrict__ gcur, unsigned int* __restrict__ bout){
  __shared__ int lcnt[256], gbase[256];
  int t = threadIdx.x;
  lcnt[t] = 0;
  __syncthreads();
  int base = blockIdx.x*BCHUNK;
  int end = min(base + BCHUNK, E);
  for (int i = base + t; i < end; i += 256) atomicAdd(&lcnt[dst[i] >> 9], 1);
  __syncthreads();
  gbase[t] = lcnt[t] ? atomicAdd(&gcur[t], lcnt[t]) : 0;
  __syncthreads();
  lcnt[t] = 0;
  __syncthreads();
  for (int i = base + t; i < end; i += 256){
    int s = src[i], d = dst[i];
    int b = d >> 9;
    int pos = gbase[b] + atomicAdd(&lcnt[b], 1);
    bout[pos] = ((unsigned int)s << 9) | (unsigned int)(d & 511);
  }
}

__global__ __launch_bounds__(256) void k_build(const unsigned int* __restrict__ bout, const int* __restrict__ bbase,
                       int* __restrict__ rowptr, float* __restrict__ dinv,
                       int* __restrict__ cols, int N, int NB){
  __shared__ int cnt[512], part[256];
  int b = blockIdx.x;
  int t = threadIdx.x;
  cnt[t] = 0; cnt[t + 256] = 0;
  __syncthreads();
  int s0 = bbase[b], s1 = bbase[b+1];
  for (int i = s0 + t; i < s1; i += 256) atomicAdd(&cnt[bout[i] & 511u], 1);
  __syncthreads();
  int c0 = cnt[2*t], c1 = cnt[2*t + 1];
  part[t] = c0 + c1;
  __syncthreads();
  for (int o = 1; o < 256; o <<= 1){
    int u = (t >= o) ? part[t-o] : 0;
    __syncthreads();
    part[t] += u;
    __syncthreads();
  }
  int e0 = part[t] - (c0 + c1);
  int e1 = e0 + c0;
  int r0 = b << 9;
  int n0 = r0 + 2*t, n1 = n0 + 1;
  if (n0 < N){ rowptr[n0] = s0 + e0; dinv[n0] = rsqrtf((float)c0 + 2.f); }
  if (n1 < N){ rowptr[n1] = s0 + e1; dinv[n1] = rsqrtf((float)c1 + 2.f); }
  if (b == NB-1 && t == 0) rowptr[N] = s1;
  __syncthreads();
  cnt[2*t] = s0 + e0; cnt[2*t + 1] = s0 + e1;   // reuse as cursors
  __syncthreads();
  for (int i = s0 + t; i < s1; i += 256){
    unsigned int v = bout[i];
    int pos = atomicAdd(&cnt[v & 511u], 1);
    cols[pos] = (int)(v >> 9);
  }
}

// ---- CSR level L+1 from level L: wave-parallel (16 lanes/row), order-preserving ----

__global__ __launch_bounds__(256) void k_csr_keep(const int* __restrict__ rowptrA, const int* __restrict__ colsA,
                         const int* __restrict__ nidx, int* __restrict__ tmp,
                         int* __restrict__ cnt, int NA){
  int t = threadIdx.x;
  int g = (blockIdx.x*256 + t) >> 4;
  int lane = t & 15;
  if (g >= NA) return;
  int m = nidx[g];
  if (m < 0) return;
  int jb = rowptrA[g], je = rowptrA[g+1];
  int run = 0;
  int shift = (t & 63) & ~15;
  for (int j0 = jb; j0 < je; j0 += 16){
    int j = j0 + lane;
    int s = -1;
    if (j < je) s = nidx[colsA[j]];
    bool keep = s >= 0;
    unsigned long long bal = __ballot(keep);
    unsigned int gm = (unsigned int)(bal >> shift) & 0xFFFFu;
    if (keep) tmp[jb + run + __popc(gm & ((1u << lane) - 1))] = s;
    run += __popc(gm);
  }
  if (lane == 0) cnt[m] = run;
}

__global__ __launch_bounds__(256) void k_csr_copy(const int* __restrict__ rowptrA, const int* __restrict__ nidx,
                         const int* __restrict__ tmp, const int* __restrict__ rowptrB,
                         int* __restrict__ colsB, int NA){
  int t = threadIdx.x;
  int g = (blockIdx.x*256 + t) >> 4;
  int lane = t & 15;
  if (g >= NA) return;
  int m = nidx[g];
  if (m < 0) return;
  int jbA = rowptrA[g];
  int db = rowptrB[m], n = rowptrB[m+1] - db;
  for (int j = lane; j < n; j += 16) colsB[db + j] = tmp[jbA + j];
}

// ---------------- hierarchical exclusive scan (for derived CSR levels) ----------------

__global__ __launch_bounds__(256) void k_scan_p1(const int* __restrict__ in, int nIn, int* __restrict__ bsum){
  __shared__ int sh[256];
  int base = blockIdx.x*SCAN_CHUNK;
  int end = min(base + SCAN_CHUNK, nIn);
  int s = 0;
  for (int i = base + threadIdx.x; i < end; i += 256) s += in[i];
  sh[threadIdx.x] = s; __syncthreads();
  for (int o = 128; o > 0; o >>= 1){
    if (threadIdx.x < o) sh[threadIdx.x] += sh[threadIdx.x + o];
    __syncthreads();
  }
  if (threadIdx.x == 0) bsum[blockIdx.x] = sh[0];
}

__global__ __launch_bounds__(256) void k_scan_p2(int* __restrict__ bsum, int nb){
  __shared__ int sh[256];
  int t = threadIdx.x;
  int v = (t < nb) ? bsum[t] : 0;
  sh[t] = v; __syncthreads();
  for (int o = 1; o < 256; o <<= 1){
    int u = (t >= o) ? sh[t-o] : 0;
    __syncthreads();
    sh[t] += u;
    __syncthreads();
  }
  if (t < nb) bsum[t] = sh[t] - v;
}

__global__ __launch_bounds__(256) void k_scan_p3(const int* __restrict__ cnt, const int* __restrict__ bsum,
                        int* __restrict__ rowptr, float* __restrict__ dinv, int nIn){
  int t = threadIdx.x;
  int tb = blockIdx.x*SCAN_CHUNK + t*16;
  int my[16]; int s = 0;
#pragma unroll
  for (int j = 0; j < 16; ++j){
    int i = tb + j;
    int v = (i < nIn) ? cnt[i] : 0;
    my[j] = v; s += v;
  }
  __shared__ int sh[256];
  sh[t] = s; __syncthreads();
  for (int o = 1; o < 256; o <<= 1){
    int u = (t >= o) ? sh[t-o] : 0;
    __syncthreads();
    sh[t] += u;
    __syncthreads();
  }
  int run = bsum[blockIdx.x] + sh[t] - s;
#pragma unroll
  for (int j = 0; j < 16; ++j){
    int i = tb + j;
    if (i < nIn){
      rowptr[i] = run;
      if (dinv) dinv[i] = rsqrtf((float)my[j] + 2.0f);
      run += my[j];
    } else if (i == nIn){
      rowptr[nIn] = run;
    }
  }
}

// ---------------- W prep (element-parallel) ----------------

__global__ void k_prep_w_el(const float* __restrict__ W, const float* __restrict__ ss,
                            _Float16* __restrict__ Whi, _Float16* __restrict__ Wlo,
                            float* __restrict__ bias2, const float* __restrict__ bias,
                            int KM, int M, int mshift, int mmask){
  int idx = blockIdx.x*256 + threadIdx.x;
  if (idx >= KM) return;
  int k = idx >> mshift, m = idx & mmask;
  float w = W[idx];
  if (ss) w *= ss[k];
  _Float16 hi = (_Float16)w;
  size_t oidx = ((size_t)(k >> 2)*M + m)*4 + (k & 3);
  Whi[oidx] = hi;
  if (Wlo) Wlo[oidx] = (_Float16)(w - (float)hi);
  if (k == 0) bias2[m] = bias ? bias[m] : 0.f;
}

__global__ void k_prep_bias(const float* __restrict__ W, const float* __restrict__ ss,
                            float* __restrict__ bias2, int K, int M){
  int m = blockIdx.x;
  int lane = threadIdx.x;
  float s = 0.f;
  for (int k = lane; k < K; k += 64) s = fmaf(ss[K + k], W[(size_t)k*M + m], s);
  for (int o = 32; o > 0; o >>= 1) s += __shfl_down(s, o, 64);
  if (lane == 0) bias2[m] = s;
}

// ---------------- MFMA f16 GEMM, 64 rows/wave, optional pooled-A (perm+val) ----------------

template<int SPLIT>
__global__ __launch_bounds__(256) void k_gemm16(
    const float* __restrict__ A, const _Float16* __restrict__ Whi,
    const _Float16* __restrict__ Wlo, const float* __restrict__ bias2,
    float* __restrict__ Out32, _Float16* __restrict__ Out16,
    float* __restrict__ stats, const int* __restrict__ permA,
    const float* __restrict__ valA, int N, int K, int M, int relu)
{
  __shared__ float sacc[64], s2acc[64];
  int tid = threadIdx.x;
  if (stats){
    if (tid < 64){ sacc[tid] = 0.f; s2acc[tid] = 0.f; }
    __syncthreads();
  }
  int wave = tid >> 6, lane = tid & 63;
  int g = lane >> 4, r = lane & 15;
  int wrow0 = blockIdx.x*256 + wave*64;
  int col0 = blockIdx.y*64;
  int nf = (M - col0) >> 4; if (nf > 4) nf = 4;

  int srow[4]; float sclr[4];
#pragma unroll
  for (int rt = 0; rt < 4; ++rt){
    int arow = wrow0 + rt*16 + r;
    if (arow < N){
      int sr = permA ? permA[arow] : arow;
      srow[rt] = sr;
      sclr[rt] = permA ? valA[sr] : 1.f;
    } else { srow[rt] = -1; sclr[rt] = 0.f; }
  }

  v4f acc[4][4];
#pragma unroll
  for (int rt = 0; rt < 4; ++rt)
#pragma unroll
    for (int c = 0; c < 4; ++c) acc[rt][c] = (v4f){0.f,0.f,0.f,0.f};

  for (int k0 = 0; k0 < K; k0 += 16){
    int kb = (k0 >> 2) + g;
    v4h bh[4], bl[4];
#pragma unroll
    for (int c = 0; c < 4; ++c){
      if (c >= nf) continue;
      size_t bidx = ((size_t)kb*M + col0 + c*16 + r)*4;
      bh[c] = *(const v4h*)&Whi[bidx];
      if (SPLIT) bl[c] = *(const v4h*)&Wlo[bidx];
    }
    v4h ah[4], al[4];
#pragma unroll
    for (int rt = 0; rt < 4; ++rt){
      if (srow[rt] >= 0){
        float4 av = *(const float4*)&A[(size_t)srow[rt]*K + k0 + g*4];
        float xs[4] = {av.x*sclr[rt], av.y*sclr[rt], av.z*sclr[rt], av.w*sclr[rt]};
#pragma unroll
        for (int j = 0; j < 4; ++j){
          _Float16 hi = (_Float16)xs[j];
          ah[rt][j] = hi;
          if (SPLIT) al[rt][j] = (_Float16)(xs[j] - (float)hi);
        }
      } else {
#pragma unroll
        for (int j = 0; j < 4; ++j){ ah[rt][j] = (_Float16)0.f; if (SPLIT) al[rt][j] = (_Float16)0.f; }
      }
    }
#pragma unroll
    for (int rt = 0; rt < 4; ++rt){
#pragma unroll
      for (int c = 0; c < 4; ++c){
        if (c >= nf) continue;
        acc[rt][c] = __builtin_amdgcn_mfma_f32_16x16x16f16(ah[rt], bh[c], acc[rt][c], 0, 0, 0);
        if (SPLIT){
          acc[rt][c] = __builtin_amdgcn_mfma_f32_16x16x16f16(al[rt], bh[c], acc[rt][c], 0, 0, 0);
          acc[rt][c] = __builtin_amdgcn_mfma_f32_16x16x16f16(ah[rt], bl[c], acc[rt][c], 0, 0, 0);
        }
      }
    }
  }

#pragma unroll
  for (int c = 0; c < 4; ++c){
    if (c >= nf) continue;
    int col = col0 + c*16 + r;
    float bsv = bias2[col];
    float s = 0.f, s2 = 0.f;
#pragma unroll
    for (int rt = 0; rt < 4; ++rt){
#pragma unroll
      for (int i = 0; i < 4; ++i){
        int rr = wrow0 + rt*16 + g*4 + i;
        float v = acc[rt][c][i] + bsv;
        if (relu) v = fmaxf(v, 0.f);
        if (rr < N){
          if (Out32) Out32[(size_t)rr*M + col] = v;
          if (Out16) Out16[(size_t)rr*M + col] = (_Float16)v;
          s += v; s2 = fmaf(v, v, s2);
        }
      }
    }
    if (stats){
      s  += __shfl_xor(s, 16);  s  += __shfl_xor(s, 32);
      s2 += __shfl_xor(s2, 16); s2 += __shfl_xor(s2, 32);
      if (g == 0){
        atomicAdd(&sacc[c*16 + r], s);
        atomicAdd(&s2acc[c*16 + r], s2);
      }
    }
  }
  if (stats){
    __syncthreads();
    if (tid < 64 && col0 + tid < M){
      atomicAdd(&stats[col0 + tid], sacc[tid]);
      atomicAdd(&stats[M + col0 + tid], s2acc[tid]);
    }
  }
}

// ---------------- batch norm ----------------

__global__ void k_bn_stats(const float* __restrict__ X, float* __restrict__ acc, int N, int C){
  int col = threadIdx.x % C;
  int rg  = threadIdx.x / C;
  int R   = blockDim.x / C;
  float s = 0.f, s2 = 0.f;
  for (int r = blockIdx.x*R + rg; r < N; r += gridDim.x*R){
    float v = X[(size_t)r*C + col];
    s += v; s2 += v*v;
  }
  __shared__ float sh[256], sh2[256];
  sh[threadIdx.x] = s; sh2[threadIdx.x] = s2;
  __syncthreads();
  if (rg == 0){
    for (int r = 1; r < R; ++r){ s += sh[r*C + col]; s2 += sh2[r*C + col]; }
    atomicAdd(&acc[col], s);
    atomicAdd(&acc[C + col], s2);
  }
}

__global__ void k_bn_final(const float* __restrict__ acc, const float* __restrict__ g,
                           const float* __restrict__ b, float* __restrict__ ss, int N, int C){
  int c = threadIdx.x;
  if (c >= C) return;
  float mu  = acc[c] / (float)N;
  float var = acc[C + c] / (float)N - mu*mu;
  float sc  = rsqrtf(var + 1e-5f) * g[c];
  ss[c]     = sc;
  ss[C + c] = b[c] - mu*sc;
}

__global__ void k_bn_apply(const float* __restrict__ X, float* __restrict__ Y,
                           const float* __restrict__ ss, int total, int C, int relu){
  int i = blockIdx.x*blockDim.x + threadIdx.x;
  if (i >= total) return;
  int c = i % C;
  float v = X[i]*ss[c] + ss[C + c];
  if (relu) v = fmaxf(v, 0.f);
  Y[i] = v;
}

// fused BN-apply(+relu) + pooling score (one wave per node)
__global__ void k_bnap_score(const float* __restrict__ X, float* __restrict__ Y,
                             const float* __restrict__ ss, const float* __restrict__ p,
                             float* __restrict__ val, unsigned int* __restrict__ key,
                             int N, int C){
  int wid  = (blockIdx.x*blockDim.x + threadIdx.x) >> 6;
  int lane = threadIdx.x & 63;
  if (wid >= N) return;
  float s = 0.f, np = 0.f;
  for (int c = lane; c < C; c += 64){
    float v = X[(size_t)wid*C + c]*ss[c] + ss[C + c];
    v = fmaxf(v, 0.f);
    Y[(size_t)wid*C + c] = v;
    float pv = p[c];
    s = fmaf(v, pv, s);
    np = fmaf(pv, pv, np);
  }
  for (int o = 32; o > 0; o >>= 1){ s += __shfl_down(s, o, 64); np += __shfl_down(np, o, 64); }
  if (lane == 0){
    float sc = tanhf(s * rsqrtf(np));
    val[wid] = sc;
    unsigned int b = __float_as_uint(sc);
    key[wid] = (b & 0x80000000u) ? ~b : (b | 0x80000000u);
  }
}

// ---------------- GCN aggregation (pair-vectorized + 4-edge ILP) ----------------

__device__ inline float2 ldpair(const float* h, size_t off){
  return *(const float2*)(h + off);
}
__device__ inline float2 ldpair(const _Float16* h, size_t off){
  h2 v = *(const h2*)(h + off);
  return make_float2((float)v[0], (float)v[1]);
}

template<int C, typename T>
__global__ void k_agg(const T* __restrict__ h, const int* __restrict__ rowptr,
                      const int* __restrict__ cols, const float* __restrict__ dinv,
                      const float* __restrict__ bias, float* __restrict__ out,
                      int N, int relu)
{
  constexpr int PAIRS = C/2;
  constexpr int TPN = (PAIRS < 64) ? PAIRS : 64;
  constexpr int R = PAIRS / TPN;
  int gid  = blockIdx.x*blockDim.x + threadIdx.x;
  int node = gid / TPN;
  int lane = gid % TPN;
  if (node >= N) return;
  float di = dinv[node];
  float2 acc[R];
#pragma unroll
  for (int r = 0; r < R; ++r) acc[r] = make_float2(0.f, 0.f);
  int j  = rowptr[node];
  int je = rowptr[node+1];
  for (; j + 4 <= je; j += 4){
    int s0 = cols[j], s1 = cols[j+1], s2 = cols[j+2], s3 = cols[j+3];
    float w0 = dinv[s0]*di, w1 = dinv[s1]*di, w2 = dinv[s2]*di, w3 = dinv[s3]*di;
#pragma unroll
    for (int r = 0; r < R; ++r){
      size_t po = (size_t)(lane + r*TPN)*2;
      float2 h0 = ldpair(h, (size_t)s0*C + po);
      float2 h1 = ldpair(h, (size_t)s1*C + po);
      float2 h2v = ldpair(h, (size_t)s2*C + po);
      float2 h3 = ldpair(h, (size_t)s3*C + po);
      acc[r].x = fmaf(w0, h0.x, acc[r].x); acc[r].y = fmaf(w0, h0.y, acc[r].y);
      acc[r].x = fmaf(w1, h1.x, acc[r].x); acc[r].y = fmaf(w1, h1.y, acc[r].y);
      acc[r].x = fmaf(w2, h2v.x, acc[r].x); acc[r].y = fmaf(w2, h2v.y, acc[r].y);
      acc[r].x = fmaf(w3, h3.x, acc[r].x); acc[r].y = fmaf(w3, h3.y, acc[r].y);
    }
  }
  for (; j < je; ++j){
    int s = cols[j];
    float wgt = dinv[s]*di;
#pragma unroll
    for (int r = 0; r < R; ++r){
      float2 hv = ldpair(h, (size_t)s*C + (size_t)(lane + r*TPN)*2);
      acc[r].x = fmaf(wgt, hv.x, acc[r].x);
      acc[r].y = fmaf(wgt, hv.y, acc[r].y);
    }
  }
  float sw = 2.f*di*di;
#pragma unroll
  for (int r = 0; r < R; ++r){
    int pc = (lane + r*TPN)*2;
    float2 hv = ldpair(h, (size_t)node*C + pc);
    float2 v;
    v.x = acc[r].x + sw*hv.x + bias[pc];
    v.y = acc[r].y + sw*hv.y + bias[pc+1];
    if (relu){ v.x = fmaxf(v.x, 0.f); v.y = fmaxf(v.y, 0.f); }
    *(float2*)&out[(size_t)node*C + pc] = v;
  }
}

template<typename T>
static void launch_agg(const T* h, const int* rp, const int* cl, const float* dv,
                       const float* bias, float* o, int N, int C, int relu, hipStream_t stream){
  int tpn = (C/2 < 64) ? C/2 : 64;
  dim3 g(cdiv(N*tpn, 256));
  switch (C){
    case 16:  k_agg<16,T> <<<g, dim3(256), 0, stream>>>(h, rp, cl, dv, bias, o, N, relu); break;
    case 64:  k_agg<64,T> <<<g, dim3(256), 0, stream>>>(h, rp, cl, dv, bias, o, N, relu); break;
    case 128: k_agg<128,T><<<g, dim3(256), 0, stream>>>(h, rp, cl, dv, bias, o, N, relu); break;
    case 256: k_agg<256,T><<<g, dim3(256), 0, stream>>>(h, rp, cl, dv, bias, o, N, relu); break;
  }
}

// ---------------- top-k selection machinery ----------------

__global__ void k_hist_hi(const unsigned int* __restrict__ key, int N, unsigned int* __restrict__ hist){
  int i = blockIdx.x*blockDim.x + threadIdx.x;
  if (i < N) atomicAdd(&hist[key[i] >> 16], 1u);
}

__global__ void k_hist_lo(const unsigned int* __restrict__ key, int N,
                          const int* __restrict__ state, unsigned int* __restrict__ hist){
  int i = blockIdx.x*blockDim.x + threadIdx.x;
  if (i >= N) return;
  unsigned int kk = key[i];
  if ((int)(kk >> 16) == state[1]) atomicAdd(&hist[kk & 0xffffu], 1u);
}

__global__ __launch_bounds__(256) void k_hsum(const unsigned int* __restrict__ hist, unsigned int* __restrict__ hsum){
  __shared__ unsigned int sh[256];
  unsigned int v = hist[blockIdx.x*256 + threadIdx.x];
  sh[threadIdx.x] = v; __syncthreads();
  for (int o = 128; o > 0; o >>= 1){
    if (threadIdx.x < o) sh[threadIdx.x] += sh[threadIdx.x + o];
    __syncthreads();
  }
  if (threadIdx.x == 0) hsum[blockIdx.x] = sh[0];
}

__global__ __launch_bounds__(256) void k_hpick(const unsigned int* __restrict__ hist, const unsigned int* __restrict__ hsum,
                       int* __restrict__ state, int karg, int kidx, int bidx, int ridx){
  __shared__ unsigned int sh[256];
  __shared__ int Bsel;
  __shared__ unsigned int aboveB;
  int t = threadIdx.x;
  unsigned int v = hsum[t];
  sh[t] = v; __syncthreads();
  for (int o = 1; o < 256; o <<= 1){            // suffix-inclusive
    unsigned int u = (t + o < 256) ? sh[t + o] : 0u;
    __syncthreads();
    sh[t] += u;
    __syncthreads();
  }
  unsigned int k = (unsigned int)((kidx >= 0) ? state[kidx] : karg);
  unsigned int above = sh[t] - v;
  if (above < k && sh[t] >= k){ Bsel = t; aboveB = above; }
  __syncthreads();
  int B = Bsel; unsigned int ab = aboveB;
  unsigned int c = hist[B*256 + t];
  sh[t] = c; __syncthreads();
  for (int o = 1; o < 256; o <<= 1){
    unsigned int u = (t + o < 256) ? sh[t + o] : 0u;
    __syncthreads();
    sh[t] += u;
    __syncthreads();
  }
  unsigned int above2 = ab + sh[t] - c;
  if (above2 < k && above2 + c >= k){ state[bidx] = B*256 + t; state[ridx] = (int)(k - above2); }
}

__global__ __launch_bounds__(256) void k_sel_p1(const unsigned int* __restrict__ key, int n,
                       const int* __restrict__ state, int2* __restrict__ bcnt){
  unsigned int T = ((unsigned int)state[1] << 16) | (unsigned int)state[3];
  int base = blockIdx.x*SCAN_CHUNK;
  int end = min(base + SCAN_CHUNK, n);
  int gt = 0, eq = 0;
  for (int i = base + threadIdx.x; i < end; i += 256){
    unsigned int v = key[i];
    gt += (v > T); eq += (v == T);
  }
  __shared__ int sg[256], se[256];
  sg[threadIdx.x] = gt; se[threadIdx.x] = eq;
  __syncthreads();
  for (int o = 128; o > 0; o >>= 1){
    if (threadIdx.x < o){ sg[threadIdx.x] += sg[threadIdx.x + o]; se[threadIdx.x] += se[threadIdx.x + o]; }
    __syncthreads();
  }
  if (threadIdx.x == 0) bcnt[blockIdx.x] = make_int2(sg[0], se[0]);
}

__global__ __launch_bounds__(256) void k_sel_p2(int2* __restrict__ bcnt, int nb){
  __shared__ int sg[256], se[256];
  int t = threadIdx.x;
  int2 v = (t < nb) ? bcnt[t] : make_int2(0, 0);
  sg[t] = v.x; se[t] = v.y; __syncthreads();
  for (int o = 1; o < 256; o <<= 1){
    int a = (t >= o) ? sg[t-o] : 0;
    int b = (t >= o) ? se[t-o] : 0;
    __syncthreads();
    sg[t] += a; se[t] += b;
    __syncthreads();
  }
  if (t < nb) bcnt[t] = make_int2(sg[t] - v.x, se[t] - v.y);
}

__global__ __launch_bounds__(256) void k_sel_p3(const unsigned int* __restrict__ key, int n,
                       const int* __restrict__ state, const int2* __restrict__ bcnt,
                       int* __restrict__ nidx, int* __restrict__ perm){
  unsigned int T = ((unsigned int)state[1] << 16) | (unsigned int)state[3];
  int m = state[4];
  int t = threadIdx.x;
  int tb = blockIdx.x*SCAN_CHUNK + t*16;
  unsigned int kk[16];
  int gt = 0, eq = 0;
#pragma unroll
  for (int j = 0; j < 16; ++j){
    int i = tb + j;
    bool ok = i < n;
    unsigned int v = ok ? key[i] : 0u;
    kk[j] = v;
    gt += (ok && v > T); eq += (ok && v == T);
  }
  __shared__ unsigned long long sh[256];
  unsigned long long mine = ((unsigned long long)(unsigned)gt << 32) | (unsigned)eq;
  sh[t] = mine; __syncthreads();
  for (int o = 1; o < 256; o <<= 1){
    unsigned long long u = (t >= o) ? sh[t-o] : 0ull;
    __syncthreads();
    sh[t] += u;
    __syncthreads();
  }
  unsigned long long excl = sh[t] - mine;
  int2 bo = bcnt[blockIdx.x];
  int gb = bo.x + (int)(excl >> 32);
  int eb = bo.y + (int)(excl & 0xffffffffu);
#pragma unroll
  for (int j = 0; j < 16; ++j){
    int i = tb + j;
    if (i >= n) break;
    unsigned int v = kk[j];
    bool g = v > T, e = v == T;
    bool sel = g || (e && eb < m);
    if (sel){
      int ni = gb + (eb < m ? eb : m);
      nidx[i] = ni;
      perm[ni] = i;
    } else nidx[i] = -1;
    gb += g; eb += e;
  }
}

__global__ void k_unpool(float* __restrict__ X, const float* __restrict__ D,
                         const int* __restrict__ nidx, int N, int C){
  int i = blockIdx.x*blockDim.x + threadIdx.x;
  int n = i / C, c = i % C;
  if (n >= N) return;
  int m = nidx[n];
  if (m >= 0) X[i] = (D[(size_t)m*C + c] + X[i])*0.5f;
}

// ---------------- launch ----------------

extern "C" void kernel_launch(void* const* d_in, const int* in_sizes, int n_in,
                              void* d_out, int out_size, void* d_ws, size_t ws_size,
                              hipStream_t stream)
{
  const float* x_in = (const float*)d_in[0];
  const int*   esrc = (const int*)d_in[1];
  const int*   edst = (const int*)d_in[2];
  const float* e0_mlp_W = (const float*)d_in[3];
  const float* e0_mlp_b = (const float*)d_in[4];
  const float* e0_bn1_g = (const float*)d_in[5];
  const float* e0_bn1_b = (const float*)d_in[6];
  const float* e0_conv_W= (const float*)d_in[7];
  const float* e0_conv_b= (const float*)d_in[8];
  const float* e0_n_g   = (const float*)d_in[9];
  const float* e0_n_b   = (const float*)d_in[10];
  const float* e1_p     = (const float*)d_in[11];
  const float* e1_mlp_W = (const float*)d_in[12];
  const float* e1_mlp_b = (const float*)d_in[13];
  const float* e1_bn1_g = (const float*)d_in[14];
  const float* e1_bn1_b = (const float*)d_in[15];
  const float* e1_conv_W= (const float*)d_in[16];
  const float* e1_conv_b= (const float*)d_in[17];
  const float* e1_n_g   = (const float*)d_in[18];
  const float* e1_n_b   = (const float*)d_in[19];
  const float* e2_p     = (const float*)d_in[20];
  const float* e2_mlp_W = (const float*)d_in[21];
  const float* e2_mlp_b = (const float*)d_in[22];
  const float* e2_bn1_g = (const float*)d_in[23];
  const float* e2_bn1_b = (const float*)d_in[24];
  const float* e2_conv_W= (const float*)d_in[25];
  const float* e2_conv_b= (const float*)d_in[26];
  const float* e2_n_g   = (const float*)d_in[27];
  const float* e2_n_b   = (const float*)d_in[28];
  const float* d2_W = (const float*)d_in[29];
  const float* d2_b = (const float*)d_in[30];
  const float* d1_W = (const float*)d_in[31];
  const float* d1_b = (const float*)d_in[32];
  const float* d0_W = (const float*)d_in[33];
  const float* d0_b = (const float*)d_in[34];
  float* out = (float*)d_out;

  const int N0 = in_sizes[0] / 16;
  const int E  = in_sizes[1];
  const int N1 = (N0 + 1) / 2;
  const int N2 = (N1 + 1) / 2;
  const int NB0 = cdiv(N0, 512);

  // ---- workspace carve ----
  char* w = (char*)d_ws;
  auto alloc = [&](size_t b)->void*{ void* p = (void*)w; w += (b + 255) & ~(size_t)255; return p; };
  float* x1 = (float*)alloc((size_t)N0*64*4);
  float* x2 = (float*)alloc((size_t)N1*128*4);
  float* x3 = (float*)alloc((size_t)N2*256*4);
  size_t tmax = (size_t)N0*64*4;
  float* tA = (float*)alloc(tmax);
  float* tB = (float*)alloc(tmax);
  _Float16* h16 = (_Float16*)alloc((size_t)N0*64*2);
  int* rowptr0 = (int*)alloc((size_t)(N0+1)*4);
  int* rowptr1 = (int*)alloc((size_t)(N1+1)*4);
  int* rowptr2 = (int*)alloc((size_t)(N2+1)*4);
  int* cnt  = (int*)alloc((size_t)(N0+1)*4);
  int* cols0 = (int*)alloc((size_t)E*4);
  int* cols1 = (int*)alloc((size_t)E*4);
  int* cols2 = (int*)alloc((size_t)E*4);
  float* dinv0 = (float*)alloc((size_t)N0*4);
  float* dinv1 = (float*)alloc((size_t)N1*4);
  float* dinv2 = (float*)alloc((size_t)N2*4);
  int* nidx1 = (int*)alloc((size_t)N0*4);
  int* nidx2 = (int*)alloc((size_t)N1*4);
  int* perm1 = (int*)alloc((size_t)N1*4);
  int* perm2 = (int*)alloc((size_t)N2*4);
  float* val = (float*)alloc((size_t)N0*4);
  unsigned int* key = (unsigned int*)alloc((size_t)N0*4);
  unsigned int* hist = (unsigned int*)alloc((size_t)65536*4);
  unsigned int* hsum = (unsigned int*)alloc(256*4);
  int* state = (int*)alloc(64);
  int* bsum = (int*)alloc(1024*4);
  int2* bcnt = (int2*)alloc(1024*8);
  int* gcur = (int*)alloc(256*4);
  int* bcnt256 = (int*)alloc(256*4);
  int* bbase = (int*)alloc(257*4);
  float* bnacc = (float*)alloc(512*4);
  float* ss = (float*)alloc(512*4);
  _Float16* whi = (_Float16*)alloc((size_t)256*256*2);
  _Float16* wlo = (_Float16*)alloc((size_t)256*256*2);
  float* bias2 = (float*)alloc(256*4);
  if ((size_t)(w - (char*)d_ws) > ws_size) return;
  unsigned int* bout = (unsigned int*)tA;   // alias (CSR0 build window)
  int* tmpE = (int*)tA;                     // alias (CSR-derive window)

  auto run_prep = [&](const float* W, const float* bias, int K, int M, int split){
    int KM = K*M;
    k_prep_w_el<<<dim3(cdiv(KM,256)), dim3(256), 0, stream>>>(
        W, nullptr, whi, split ? wlo : nullptr, bias2, bias, KM, M, __builtin_ctz(M), M-1);
  };
  auto run_prep_bn = [&](const float* W, const float* g, const float* b, int Ncount, int K, int M, int split){
    k_bn_final<<<dim3(1), dim3(K), 0, stream>>>(bnacc, g, b, ss, Ncount, K);
    int KM = K*M;
    k_prep_w_el<<<dim3(cdiv(KM,256)), dim3(256), 0, stream>>>(
        W, ss, whi, split ? wlo : nullptr, bias2, nullptr, KM, M, __builtin_ctz(M), M-1);
    k_prep_bias<<<dim3(M), dim3(64), 0, stream>>>(W, ss, bias2, K, M);
  };
  auto run_gemm = [&](const float* A, float* O32, _Float16* O16, float* stats,
                      const int* perm, int N, int K, int M, int act, int split){
    dim3 grd(cdiv(N,256), cdiv(M,64));
    if (split)
      k_gemm16<1><<<grd, dim3(256), 0, stream>>>(A, whi, wlo, bias2, O32, O16, stats, perm, val, N, K, M, act);
    else
      k_gemm16<0><<<grd, dim3(256), 0, stream>>>(A, whi, wlo, bias2, O32, O16, stats, perm, val, N, K, M, act);
  };
  auto run_scan = [&](const int* in, int* rowptr, float* dinv, int nIn){
    int nb = cdiv(nIn + 1, SCAN_CHUNK);
    k_scan_p1<<<dim3(nb), dim3(256), 0, stream>>>(in, nIn, bsum);
    k_scan_p2<<<dim3(1), dim3(256), 0, stream>>>(bsum, nb);
    k_scan_p3<<<dim3(nb), dim3(256), 0, stream>>>(in, bsum, rowptr, dinv, nIn);
  };
  auto run_topk_rest = [&](int N, int k, int* nidx, int* perm){
    hipMemsetAsync(hist, 0, 65536*4, stream);
    k_hist_hi<<<dim3(cdiv(N,256)), dim3(256), 0, stream>>>(key, N, hist);
    k_hsum<<<dim3(256), dim3(256), 0, stream>>>(hist, hsum);
    k_hpick<<<dim3(1), dim3(256), 0, stream>>>(hist, hsum, state, k, -1, 1, 2);
    hipMemsetAsync(hist, 0, 65536*4, stream);
    k_hist_lo<<<dim3(cdiv(N,256)), dim3(256), 0, stream>>>(key, N, state, hist);
    k_hsum<<<dim3(256), dim3(256), 0, stream>>>(hist, hsum);
    k_hpick<<<dim3(1), dim3(256), 0, stream>>>(hist, hsum, state, 0, 2, 3, 4);
    int nb = cdiv(N, SCAN_CHUNK);
    k_sel_p1<<<dim3(nb), dim3(256), 0, stream>>>(key, N, state, bcnt);
    k_sel_p2<<<dim3(1), dim3(256), 0, stream>>>(bcnt, nb);
    k_sel_p3<<<dim3(nb), dim3(256), 0, stream>>>(key, N, state, bcnt, nidx, perm);
  };
  auto run_csr_derive = [&](const int* rpA, const int* clA, const int* nidx,
                            int* rpB, int* clB, float* dvB, int NA, int NB){
    k_csr_keep<<<dim3(cdiv(NA*16,256)), dim3(256), 0, stream>>>(rpA, clA, nidx, tmpE, cnt, NA);
    run_scan(cnt, rpB, dvB, NB);
    k_csr_copy<<<dim3(cdiv(NA*16,256)), dim3(256), 0, stream>>>(rpA, nidx, tmpE, rpB, clB, NA);
  };

  // ---- CSR level 0: bucketed build (no big global atomics) ----
  hipMemsetAsync(bcnt256, 0, 256*4, stream);
  k_bcount<<<dim3(64), dim3(256), 0, stream>>>(edst, E, bcnt256);
  k_scan_b256<<<dim3(1), dim3(256), 0, stream>>>(bcnt256, bbase, gcur, NB0);
  k_bucket<<<dim3(cdiv(E,BCHUNK)), dim3(256), 0, stream>>>(esrc, edst, E, gcur, bout);
  k_build<<<dim3(NB0), dim3(256), 0, stream>>>(bout, bbase, rowptr0, dinv0, cols0, N0, NB0);

  // ---- encoder0 (split path: feeds pool1+pool2 selections) ----
  hipMemsetAsync(bnacc, 0, 2*64*4, stream);
  run_prep(e0_mlp_W, e0_mlp_b, 16, 64, 1);
  run_gemm(x_in, tA, nullptr, bnacc, nullptr, N0, 16, 64, 1, 1);
  run_prep_bn(e0_conv_W, e0_bn1_g, e0_bn1_b, N0, 64, 64, 1);
  run_gemm(tA, tB, nullptr, nullptr, nullptr, N0, 64, 64, 0, 1);
  launch_agg<float>(tB, rowptr0, cols0, dinv0, e0_conv_b, tA, N0, 64, 0, stream);
  hipMemsetAsync(bnacc, 0, 2*64*4, stream);
  k_bn_stats<<<dim3(256), dim3(256), 0, stream>>>(tA, bnacc, N0, 64);
  k_bn_final<<<dim3(1), dim3(64), 0, stream>>>(bnacc, e0_n_g, e0_n_b, ss, N0, 64);
  k_bnap_score<<<dim3(cdiv(N0*64,256)), dim3(256), 0, stream>>>(tA, x1, ss, e1_p, val, key, N0, 64);

  // ---- pool1 + CSR level 1 (derived from CSR0, wave-parallel) ----
  run_topk_rest(N0, N1, nidx1, perm1);
  run_csr_derive(rowptr0, cols0, nidx1, rowptr1, cols1, dinv1, N0, N1);

  // ---- encoder1 (split path: feeds pool2 selection; pooled-A fused) ----
  hipMemsetAsync(bnacc, 0, 2*128*4, stream);
  run_prep(e1_mlp_W, e1_mlp_b, 64, 128, 1);
  run_gemm(x1, tB, nullptr, bnacc, perm1, N1, 64, 128, 1, 1);
  run_prep_bn(e1_conv_W, e1_bn1_g, e1_bn1_b, N1, 128, 128, 1);
  run_gemm(tB, tA, nullptr, nullptr, nullptr, N1, 128, 128, 0, 1);
  launch_agg<float>(tA, rowptr1, cols1, dinv1, e1_conv_b, tB, N1, 128, 0, stream);
  hipMemsetAsync(bnacc, 0, 2*128*4, stream);
  k_bn_stats<<<dim3(256), dim3(256), 0, stream>>>(tB, bnacc, N1, 128);
  k_bn_final<<<dim3(1), dim3(128), 0, stream>>>(bnacc, e1_n_g, e1_n_b, ss, N1, 128);
  k_bnap_score<<<dim3(cdiv(N1*64,256)), dim3(256), 0, stream>>>(tB, x2, ss, e2_p, val, key, N1, 128);

  // ---- pool2 + CSR level 2 ----
  run_topk_rest(N1, N2, nidx2, perm2);
  run_csr_derive(rowptr1, cols1, nidx2, rowptr2, cols2, dinv2, N1, N2);

  // ---- encoder2 (smooth path: plain f16, f16 gather; pooled-A fused) ----
  hipMemsetAsync(bnacc, 0, 2*256*4, stream);
  run_prep(e2_mlp_W, e2_mlp_b, 128, 256, 0);
  run_gemm(x2, tB, nullptr, bnacc, perm2, N2, 128, 256, 1, 0);
  run_prep_bn(e2_conv_W, e2_bn1_g, e2_bn1_b, N2, 256, 256, 0);
  run_gemm(tB, nullptr, h16, nullptr, nullptr, N2, 256, 256, 0, 0);
  launch_agg<_Float16>(h16, rowptr2, cols2, dinv2, e2_conv_b, tB, N2, 256, 0, stream);
  hipMemsetAsync(bnacc, 0, 2*256*4, stream);
  k_bn_stats<<<dim3(256), dim3(256), 0, stream>>>(tB, bnacc, N2, 256);
  k_bn_final<<<dim3(1), dim3(256), 0, stream>>>(bnacc, e2_n_g, e2_n_b, ss, N2, 256);
  k_bn_apply<<<dim3(cdiv(N2*256,256)), dim3(256), 0, stream>>>(tB, x3, ss, N2*256, 256, 1);

  // ---- decoder2 + unpool into x2 ----
  run_prep(d2_W, nullptr, 256, 128, 0);
  run_gemm(x3, nullptr, h16, nullptr, nullptr, N2, 256, 128, 0, 0);
  launch_agg<_Float16>(h16, rowptr2, cols2, dinv2, d2_b, tB, N2, 128, 1, stream);
  k_unpool<<<dim3(cdiv(N1*128,256)), dim3(256), 0, stream>>>(x2, tB, nidx2, N1, 128);

  // ---- decoder1 + unpool into x1 ----
  run_prep(d1_W, nullptr, 128, 64, 0);
  run_gemm(x2, nullptr, h16, nullptr, nullptr, N1, 128, 64, 0, 0);
  launch_agg<_Float16>(h16, rowptr1, cols1, dinv1, d1_b, tB, N1, 64, 1, stream);
  k_unpool<<<dim3(cdiv(N0*64,256)), dim3(256), 0, stream>>>(x1, tB, nidx1, N0, 64);

  // ---- decoder0 -> output ----
  run_prep(d0_W, nullptr, 64, 16, 0);
  run_gemm(x1, nullptr, h16, nullptr, nullptr, N0, 64, 16, 0, 0);
  launch_agg<_Float16>(h16, rowptr0, cols0, dinv0, d0_b, out, N0, 16, 0, stream);
}